// Round 1
// baseline (180.816 us; speedup 1.0000x reference)
//
#include <hip/hip_runtime.h>
#include <stdint.h>

// ---------- types ----------
typedef __bf16 bf16x8 __attribute__((ext_vector_type(8)));
typedef float f32x4 __attribute__((ext_vector_type(4)));
typedef float float4v __attribute__((ext_vector_type(4)));
typedef unsigned short u16x8 __attribute__((ext_vector_type(8)));

// round-to-nearest-even fp32 -> bf16
__device__ __forceinline__ unsigned short f2bf(float f) {
    unsigned u = __float_as_uint(f);
    u += 0x7fffu + ((u >> 16) & 1u);
    return (unsigned short)(u >> 16);
}

// stable softplus
__device__ __forceinline__ float softplus(float x) {
    float ax = fabsf(x);
    return fmaxf(x, 0.0f) + log1pf(__expf(-ax));
}

// async global->LDS, 16B per lane (gfx950). LDS dest is wave-uniform base +
// lane*16, so LDS layout must be contiguous in thread order (no padding).
__device__ __forceinline__ void gl_lds16(const void* gptr, void* lptr) {
    auto g = reinterpret_cast<const __attribute__((address_space(1))) void*>(
        reinterpret_cast<uintptr_t>(gptr));
    auto l = reinterpret_cast<__attribute__((address_space(3))) void*>(
        reinterpret_cast<uintptr_t>(lptr));
    __builtin_amdgcn_global_load_lds(g, l, 16, 0, 0);
}

// ---------- prep: input fp32 -> bf16 (8 elems/thread) ----------
__global__ void cvt_input_kernel(const float* __restrict__ in,
                                 unsigned short* __restrict__ out, int n8) {
    int i = blockIdx.x * blockDim.x + threadIdx.x;
    if (i >= n8) return;
    const float4v* p = (const float4v*)in + (size_t)i * 2;
    float4v a = p[0], b = p[1];
    u16x8 r;
    r[0] = f2bf(a[0]); r[1] = f2bf(a[1]); r[2] = f2bf(a[2]); r[3] = f2bf(a[3]);
    r[4] = f2bf(b[0]); r[5] = f2bf(b[1]); r[6] = f2bf(b[2]); r[7] = f2bf(b[3]);
    ((u16x8*)out)[i] = r;
}

// ---------- prep: w = mu + softplus(rho)*eps -> bf16 ----------
__global__ void prep_w_kernel(const float* __restrict__ mu,
                              const float* __restrict__ rho,
                              const float* __restrict__ eps,
                              unsigned short* __restrict__ out, int n8) {
    int i = blockIdx.x * blockDim.x + threadIdx.x;
    if (i >= n8) return;
    const float4v* pm = (const float4v*)mu  + (size_t)i * 2;
    const float4v* pr = (const float4v*)rho + (size_t)i * 2;
    const float4v* pe = (const float4v*)eps + (size_t)i * 2;
    float4v m0 = pm[0], m1 = pm[1];
    float4v r0 = pr[0], r1 = pr[1];
    float4v e0 = pe[0], e1 = pe[1];
    u16x8 r;
    r[0] = f2bf(m0[0] + softplus(r0[0]) * e0[0]);
    r[1] = f2bf(m0[1] + softplus(r0[1]) * e0[1]);
    r[2] = f2bf(m0[2] + softplus(r0[2]) * e0[2]);
    r[3] = f2bf(m0[3] + softplus(r0[3]) * e0[3]);
    r[4] = f2bf(m1[0] + softplus(r1[0]) * e1[0]);
    r[5] = f2bf(m1[1] + softplus(r1[1]) * e1[1]);
    r[6] = f2bf(m1[2] + softplus(r1[2]) * e1[2]);
    r[7] = f2bf(m1[3] + softplus(r1[3]) * e1[3]);
    ((u16x8*)out)[i] = r;
}

// ---------- GEMM: C[M,N] = A[M,K] * B[N,K]^T + bias, bf16 in / fp32 out ----
// m97 structure: 128x128 tile, BK=32, 256 threads = 4 waves in 2x2,
// each wave computes 64x64 = 4x4 tiles of 16x16x32 MFMA.
#define BM 128
#define BN 128
#define BK 32

__global__ __launch_bounds__(256)
void gemm_bt_kernel(const unsigned short* __restrict__ A,   // [M,K] bf16
                    const unsigned short* __restrict__ B,   // [N,K] bf16
                    const float* __restrict__ bias,         // [N]
                    float* __restrict__ C,                  // [M,N] fp32
                    int M, int N, int K) {
    __shared__ unsigned short lds_a[BM * BK];   // 8 KB
    __shared__ unsigned short lds_b[BN * BK];   // 8 KB

    const int t      = threadIdx.x;
    const int lane   = t & 63;
    const int wave   = t >> 6;
    const int lane16 = lane & 15;
    const int quad   = lane >> 4;
    const int wm     = wave & 1;   // wave row (0..1)
    const int wn     = wave >> 1;  // wave col (0..1)

    const int m0 = blockIdx.y * BM;
    const int n0 = blockIdx.x * BN;

    // staging map: chunk c = j*256 + t -> row = c>>2 (j*64 + t>>2), kgroup = c&3
    const int srow = t >> 2;            // 0..63
    const int skg  = (t & 3) * 8;       // 0,8,16,24

    const unsigned short* Ab = A + (size_t)m0 * K;
    const unsigned short* Bb = B + (size_t)n0 * K;

    f32x4 acc[4][4] = {};

    for (int k0 = 0; k0 < K; k0 += BK) {
        // global -> LDS async staging (4 x 16B per thread)
        gl_lds16(Ab + (size_t)srow * K        + k0 + skg, lds_a + t * 8);
        gl_lds16(Ab + (size_t)(srow + 64) * K + k0 + skg, lds_a + 2048 + t * 8);
        gl_lds16(Bb + (size_t)srow * K        + k0 + skg, lds_b + t * 8);
        gl_lds16(Bb + (size_t)(srow + 64) * K + k0 + skg, lds_b + 2048 + t * 8);
        __syncthreads();   // drains vmcnt before barrier

        bf16x8 af[4], bfr[4];
#pragma unroll
        for (int mi = 0; mi < 4; mi++)
            af[mi] = *(const bf16x8*)(lds_a + (wm * 64 + mi * 16 + lane16) * BK + quad * 8);
#pragma unroll
        for (int ni = 0; ni < 4; ni++)
            bfr[ni] = *(const bf16x8*)(lds_b + (wn * 64 + ni * 16 + lane16) * BK + quad * 8);

#pragma unroll
        for (int mi = 0; mi < 4; mi++)
#pragma unroll
            for (int ni = 0; ni < 4; ni++)
                acc[mi][ni] = __builtin_amdgcn_mfma_f32_16x16x32_bf16(
                    af[mi], bfr[ni], acc[mi][ni], 0, 0, 0);
        __syncthreads();   // protect LDS before next stage
    }

    // epilogue: C/D layout col=lane&15, row=quad*4+reg (m89-verified)
    float bv[4];
#pragma unroll
    for (int ni = 0; ni < 4; ni++)
        bv[ni] = bias[n0 + wn * 64 + ni * 16 + lane16];

#pragma unroll
    for (int mi = 0; mi < 4; mi++) {
        const int rbase = m0 + wm * 64 + mi * 16 + quad * 4;
#pragma unroll
        for (int ni = 0; ni < 4; ni++) {
            const int col = n0 + wn * 64 + ni * 16 + lane16;
#pragma unroll
            for (int r = 0; r < 4; r++)
                C[(size_t)(rbase + r) * N + col] = acc[mi][ni][r] + bv[ni];
        }
    }
}

extern "C" void kernel_launch(void* const* d_in, const int* in_sizes, int n_in,
                              void* d_out, int out_size, void* d_ws, size_t ws_size,
                              hipStream_t stream) {
    const float* input = (const float*)d_in[0];
    const float* mu    = (const float*)d_in[1];
    const float* rho   = (const float*)d_in[2];
    const float* eps   = (const float*)d_in[3];
    const float* bias  = (const float*)d_in[4];
    float* out = (float*)d_out;

    const int OUT = in_sizes[4];              // 2048
    const int IN  = in_sizes[1] / OUT;        // 2048
    const int M   = in_sizes[0] / IN;         // 4096

    unsigned short* in_bf = (unsigned short*)d_ws;                 // M*IN bf16
    unsigned short* w_bf  = in_bf + (size_t)M * IN;                // OUT*IN bf16

    {
        int n8 = (M * IN) / 8;
        cvt_input_kernel<<<dim3((n8 + 255) / 256), 256, 0, stream>>>(input, in_bf, n8);
    }
    {
        int n8 = (OUT * IN) / 8;
        prep_w_kernel<<<dim3((n8 + 255) / 256), 256, 0, stream>>>(mu, rho, eps, w_bf, n8);
    }
    gemm_bt_kernel<<<dim3(OUT / BN, M / BM), 256, 0, stream>>>(
        in_bf, w_bf, bias, out, M, OUT, IN);
}

// Round 2
// 161.380 us; speedup vs baseline: 1.1204x; 1.1204x over previous
//
#include <hip/hip_runtime.h>
#include <stdint.h>

// ---------- types ----------
typedef __bf16 bf16x8 __attribute__((ext_vector_type(8)));
typedef float f32x4 __attribute__((ext_vector_type(4)));
typedef float float4v __attribute__((ext_vector_type(4)));
typedef unsigned short u16x8 __attribute__((ext_vector_type(8)));

// round-to-nearest-even fp32 -> bf16
__device__ __forceinline__ unsigned short f2bf(float f) {
    unsigned u = __float_as_uint(f);
    u += 0x7fffu + ((u >> 16) & 1u);
    return (unsigned short)(u >> 16);
}

// fast stable softplus: max(x,0) + log(1+exp(-|x|)); __logf/__expf are
// v_log_f32/v_exp_f32 — plenty accurate ahead of a bf16 round.
__device__ __forceinline__ float softplus(float x) {
    return fmaxf(x, 0.0f) + __logf(1.0f + __expf(-fabsf(x)));
}

// async global->LDS, 16B per lane (gfx950). LDS dest must be wave-uniform
// base + lane*16 (lane-ordered, contiguous).
__device__ __forceinline__ void gl_lds16(const void* gptr, void* lptr) {
    auto g = reinterpret_cast<const __attribute__((address_space(1))) void*>(
        reinterpret_cast<uintptr_t>(gptr));
    auto l = reinterpret_cast<__attribute__((address_space(3))) void*>(
        reinterpret_cast<uintptr_t>(lptr));
    __builtin_amdgcn_global_load_lds(g, l, 16, 0, 0);
}

// ---------- fused prep: input f32->bf16  AND  w = mu + softplus(rho)*eps ----
// One dispatch instead of two. 8 elems/thread, 32B loads, 16B stores.
__global__ void prep_kernel(const float* __restrict__ in,
                            const float* __restrict__ mu,
                            const float* __restrict__ rho,
                            const float* __restrict__ eps,
                            unsigned short* __restrict__ in_bf,
                            unsigned short* __restrict__ w_bf,
                            int nIn8, int nW8) {
    int i = blockIdx.x * blockDim.x + threadIdx.x;
    if (i < nIn8) {
        const float4v* p = (const float4v*)in + (size_t)i * 2;
        float4v a = p[0], b = p[1];
        u16x8 r;
        r[0] = f2bf(a[0]); r[1] = f2bf(a[1]); r[2] = f2bf(a[2]); r[3] = f2bf(a[3]);
        r[4] = f2bf(b[0]); r[5] = f2bf(b[1]); r[6] = f2bf(b[2]); r[7] = f2bf(b[3]);
        ((u16x8*)in_bf)[i] = r;
    } else {
        int j = i - nIn8;
        if (j >= nW8) return;
        const float4v* pm = (const float4v*)mu  + (size_t)j * 2;
        const float4v* pr = (const float4v*)rho + (size_t)j * 2;
        const float4v* pe = (const float4v*)eps + (size_t)j * 2;
        float4v m0 = pm[0], m1 = pm[1];
        float4v r0 = pr[0], r1 = pr[1];
        float4v e0 = pe[0], e1 = pe[1];
        u16x8 r;
        r[0] = f2bf(m0[0] + softplus(r0[0]) * e0[0]);
        r[1] = f2bf(m0[1] + softplus(r0[1]) * e0[1]);
        r[2] = f2bf(m0[2] + softplus(r0[2]) * e0[2]);
        r[3] = f2bf(m0[3] + softplus(r0[3]) * e0[3]);
        r[4] = f2bf(m1[0] + softplus(r1[0]) * e1[0]);
        r[5] = f2bf(m1[1] + softplus(r1[1]) * e1[1]);
        r[6] = f2bf(m1[2] + softplus(r1[2]) * e1[2]);
        r[7] = f2bf(m1[3] + softplus(r1[3]) * e1[3]);
        ((u16x8*)w_bf)[j] = r;
    }
}

// ---------- GEMM: C[M,N] = A[M,K] * B[N,K]^T + bias, bf16 in / f32 out -----
// 128x128 tile, BK=64, 512 threads = 8 waves in 2(m) x 4(n); each wave does a
// 64x32 sub-tile = 4x2 MFMA (16x16x32 bf16). Grid 16x32 = 512 blocks ->
// 2 blocks/CU x 8 waves = 16 waves/CU (vs 8 before).
// LDS k-groups XOR-swizzled (phys_kg = kg ^ (row&7)) so ds_read_b128 phases
// land 2-way on banks (free) instead of 16-way.
#define BM 128
#define BN 128
#define BK 64

__global__ __launch_bounds__(512, 4)
void gemm_bt_kernel(const unsigned short* __restrict__ A,   // [M,K] bf16
                    const unsigned short* __restrict__ B,   // [N,K] bf16
                    const float* __restrict__ bias,         // [N]
                    float* __restrict__ C,                  // [M,N] f32
                    int M, int N, int K) {
    __shared__ unsigned short lds_a[BM * BK];   // 16 KB
    __shared__ unsigned short lds_b[BN * BK];   // 16 KB

    const int t      = threadIdx.x;
    const int lane   = t & 63;
    const int wave   = t >> 6;          // 0..7
    const int lane16 = lane & 15;
    const int quad   = lane >> 4;       // 0..3
    const int wm     = wave & 1;        // wave row: 0..1 (64 rows each)
    const int wn     = wave >> 1;       // wave col: 0..3 (32 cols each)

    const int m0 = blockIdx.y * BM;
    const int n0 = blockIdx.x * BN;

    // staging: 1024 16B-chunks per tile, 512 threads -> 2 chunks each.
    // chunk c -> LDS slot c (row = c>>3, pkg = c&7); global kg = pkg ^ (row&7)
    const int r1   = t >> 3;                 // chunk t   : rows 0..63
    const int pkg1 = t & 7;
    const int g1   = (pkg1 ^ (r1 & 7)) * 8;  // element offset in row
    const int r2   = r1 + 64;                // chunk t+512: rows 64..127
    const int g2   = (pkg1 ^ (r2 & 7)) * 8;

    const unsigned short* Ab = A + (size_t)m0 * K;
    const unsigned short* Bb = B + (size_t)n0 * K;

    f32x4 acc[4][2] = {};

    // read-side swizzle: row&7 == lane16&7 for all fragment rows
    const int sw = lane16 & 7;

    for (int k0 = 0; k0 < K; k0 += BK) {
        gl_lds16(Ab + (size_t)r1 * K + k0 + g1, lds_a + t * 8);
        gl_lds16(Ab + (size_t)r2 * K + k0 + g2, lds_a + 4096 + t * 8);
        gl_lds16(Bb + (size_t)r1 * K + k0 + g1, lds_b + t * 8);
        gl_lds16(Bb + (size_t)r2 * K + k0 + g2, lds_b + 4096 + t * 8);
        __syncthreads();   // drains vmcnt before barrier

#pragma unroll
        for (int ch = 0; ch < 2; ch++) {
            const int kg = ch * 4 + quad;           // logical 16B k-group
            const int pk = (kg ^ sw) * 8;           // phys element offset
            bf16x8 af[4], bfr[2];
#pragma unroll
            for (int mi = 0; mi < 4; mi++)
                af[mi] = *(const bf16x8*)(lds_a + (wm * 64 + mi * 16 + lane16) * BK + pk);
#pragma unroll
            for (int ni = 0; ni < 2; ni++)
                bfr[ni] = *(const bf16x8*)(lds_b + (wn * 32 + ni * 16 + lane16) * BK + pk);
#pragma unroll
            for (int mi = 0; mi < 4; mi++)
#pragma unroll
                for (int ni = 0; ni < 2; ni++)
                    acc[mi][ni] = __builtin_amdgcn_mfma_f32_16x16x32_bf16(
                        af[mi], bfr[ni], acc[mi][ni], 0, 0, 0);
        }
        __syncthreads();   // protect LDS before next stage
    }

    // epilogue: C/D layout col=lane&15, row=quad*4+reg (m89-verified)
    float bv[2];
#pragma unroll
    for (int ni = 0; ni < 2; ni++)
        bv[ni] = bias[n0 + wn * 32 + ni * 16 + lane16];

#pragma unroll
    for (int mi = 0; mi < 4; mi++) {
        const int rbase = m0 + wm * 64 + mi * 16 + quad * 4;
#pragma unroll
        for (int ni = 0; ni < 2; ni++) {
            const int col = n0 + wn * 32 + ni * 16 + lane16;
#pragma unroll
            for (int r = 0; r < 4; r++)
                C[(size_t)(rbase + r) * N + col] = acc[mi][ni][r] + bv[ni];
        }
    }
}

extern "C" void kernel_launch(void* const* d_in, const int* in_sizes, int n_in,
                              void* d_out, int out_size, void* d_ws, size_t ws_size,
                              hipStream_t stream) {
    const float* input = (const float*)d_in[0];
    const float* mu    = (const float*)d_in[1];
    const float* rho   = (const float*)d_in[2];
    const float* eps   = (const float*)d_in[3];
    const float* bias  = (const float*)d_in[4];
    float* out = (float*)d_out;

    const int OUT = in_sizes[4];              // 2048
    const int IN  = in_sizes[1] / OUT;        // 2048
    const int M   = in_sizes[0] / IN;         // 4096

    unsigned short* in_bf = (unsigned short*)d_ws;                 // M*IN bf16
    unsigned short* w_bf  = in_bf + (size_t)M * IN;                // OUT*IN bf16

    const int nIn8 = (M * IN) / 8;
    const int nW8  = (OUT * IN) / 8;
    prep_kernel<<<dim3((nIn8 + nW8 + 255) / 256), 256, 0, stream>>>(
        input, mu, rho, eps, in_bf, w_bf, nIn8, nW8);

    gemm_bt_kernel<<<dim3(OUT / BN, M / BM), 512, 0, stream>>>(
        in_bf, w_bf, bias, out, M, OUT, IN);
}

// Round 3
// 159.941 us; speedup vs baseline: 1.1305x; 1.0090x over previous
//
#include <hip/hip_runtime.h>
#include <stdint.h>

// ---------- types ----------
typedef __bf16 bf16x8 __attribute__((ext_vector_type(8)));
typedef float f32x4 __attribute__((ext_vector_type(4)));
typedef float float4v __attribute__((ext_vector_type(4)));
typedef unsigned short u16x8 __attribute__((ext_vector_type(8)));

// round-to-nearest-even fp32 -> bf16
__device__ __forceinline__ unsigned short f2bf(float f) {
    unsigned u = __float_as_uint(f);
    u += 0x7fffu + ((u >> 16) & 1u);
    return (unsigned short)(u >> 16);
}

// fast stable softplus: max(x,0) + log(1+exp(-|x|))
__device__ __forceinline__ float softplus(float x) {
    return fmaxf(x, 0.0f) + __logf(1.0f + __expf(-fabsf(x)));
}

// async global->LDS, 16B per lane (gfx950). LDS dest must be wave-uniform
// base + lane*16 (lane-ordered, contiguous).
__device__ __forceinline__ void gl_lds16(const void* gptr, void* lptr) {
    auto g = reinterpret_cast<const __attribute__((address_space(1))) void*>(
        reinterpret_cast<uintptr_t>(gptr));
    auto l = reinterpret_cast<__attribute__((address_space(3))) void*>(
        reinterpret_cast<uintptr_t>(lptr));
    __builtin_amdgcn_global_load_lds(g, l, 16, 0, 0);
}

// ---------- fused prep: input f32->bf16  AND  w = mu + softplus(rho)*eps ----
__global__ void prep_kernel(const float* __restrict__ in,
                            const float* __restrict__ mu,
                            const float* __restrict__ rho,
                            const float* __restrict__ eps,
                            unsigned short* __restrict__ in_bf,
                            unsigned short* __restrict__ w_bf,
                            int nIn8, int nW8) {
    int i = blockIdx.x * blockDim.x + threadIdx.x;
    if (i < nIn8) {
        const float4v* p = (const float4v*)in + (size_t)i * 2;
        float4v a = p[0], b = p[1];
        u16x8 r;
        r[0] = f2bf(a[0]); r[1] = f2bf(a[1]); r[2] = f2bf(a[2]); r[3] = f2bf(a[3]);
        r[4] = f2bf(b[0]); r[5] = f2bf(b[1]); r[6] = f2bf(b[2]); r[7] = f2bf(b[3]);
        ((u16x8*)in_bf)[i] = r;
    } else {
        int j = i - nIn8;
        if (j >= nW8) return;
        const float4v* pm = (const float4v*)mu  + (size_t)j * 2;
        const float4v* pr = (const float4v*)rho + (size_t)j * 2;
        const float4v* pe = (const float4v*)eps + (size_t)j * 2;
        float4v m0 = pm[0], m1 = pm[1];
        float4v r0 = pr[0], r1 = pr[1];
        float4v e0 = pe[0], e1 = pe[1];
        u16x8 r;
        r[0] = f2bf(m0[0] + softplus(r0[0]) * e0[0]);
        r[1] = f2bf(m0[1] + softplus(r0[1]) * e0[1]);
        r[2] = f2bf(m0[2] + softplus(r0[2]) * e0[2]);
        r[3] = f2bf(m0[3] + softplus(r0[3]) * e0[3]);
        r[4] = f2bf(m1[0] + softplus(r1[0]) * e1[0]);
        r[5] = f2bf(m1[1] + softplus(r1[1]) * e1[1]);
        r[6] = f2bf(m1[2] + softplus(r1[2]) * e1[2]);
        r[7] = f2bf(m1[3] + softplus(r1[3]) * e1[3]);
        ((u16x8*)w_bf)[j] = r;
    }
}

// ---------- GEMM: C[M,N] = A[M,K] * B[N,K]^T + bias, bf16 in / f32 out -----
// 128x128 tile, BK=64, 512 threads = 8 waves 2(m)x4(n), wave tile 64x32.
// DOUBLE-BUFFERED LDS, ONE barrier per K-iter: per iter we (1) hoist all
// fragment ds_reads from the current buffer, (2) issue async staging of the
// NEXT buffer, (3) run 16 MFMAs, (4) barrier. The compiler's mandatory
// vmcnt(0)+lgkmcnt(0) drain at the barrier thus lands AFTER the MFMA work,
// overlapping the global->LDS latency with compute (vs R2: drain BEFORE
// compute, 58% dead cycles).
// LDS k-groups XOR-swizzled (phys_kg = kg ^ (row&7)): 0 bank conflicts (R2).
#define BM 128
#define BN 128
#define BK 64

__global__ __launch_bounds__(512, 4)
void gemm_bt_kernel(const unsigned short* __restrict__ A,   // [M,K] bf16
                    const unsigned short* __restrict__ B,   // [N,K] bf16
                    const float* __restrict__ bias,         // [N]
                    float* __restrict__ C,                  // [M,N] f32
                    int M, int N, int K) {
    __shared__ unsigned short lds_a[2][BM * BK];   // 2 x 16 KB
    __shared__ unsigned short lds_b[2][BN * BK];   // 2 x 16 KB

    const int t      = threadIdx.x;
    const int lane   = t & 63;
    const int wave   = t >> 6;          // 0..7
    const int lane16 = lane & 15;
    const int quad   = lane >> 4;       // 0..3
    const int wm     = wave & 1;        // wave row: 0..1 (64 rows each)
    const int wn     = wave >> 1;       // wave col: 0..3 (32 cols each)

    const int m0 = blockIdx.y * BM;
    const int n0 = blockIdx.x * BN;

    // staging: 1024 16B-chunks per tile, 512 threads -> 2 chunks each.
    // chunk c -> LDS slot c (row = c>>3, pkg = c&7); global kg = pkg ^ (row&7)
    const int r1   = t >> 3;                 // rows 0..63
    const int pkg1 = t & 7;
    const int g1   = (pkg1 ^ (r1 & 7)) * 8;
    const int r2   = r1 + 64;                // rows 64..127
    const int g2   = (pkg1 ^ (r2 & 7)) * 8;

    const unsigned short* Ab = A + (size_t)m0 * K;
    const unsigned short* Bb = B + (size_t)n0 * K;

    f32x4 acc[4][2] = {};
    const int sw = lane16 & 7;   // read-side swizzle key

    auto stage = [&](int buf, int k0) {
        gl_lds16(Ab + (size_t)r1 * K + k0 + g1, &lds_a[buf][t * 8]);
        gl_lds16(Ab + (size_t)r2 * K + k0 + g2, &lds_a[buf][4096 + t * 8]);
        gl_lds16(Bb + (size_t)r1 * K + k0 + g1, &lds_b[buf][t * 8]);
        gl_lds16(Bb + (size_t)r2 * K + k0 + g2, &lds_b[buf][4096 + t * 8]);
    };

    const int nit = K / BK;       // 32 (even)
    stage(0, 0);
    __syncthreads();              // drain prologue staging

    auto body = [&](int cur, int it) {
        const unsigned short* la = lds_a[cur];
        const unsigned short* lb = lds_b[cur];
        // (1) hoist ALL fragment reads from current buffer
        bf16x8 af[2][4], bfr[2][2];
#pragma unroll
        for (int ch = 0; ch < 2; ch++) {
            const int pk = ((ch * 4 + quad) ^ sw) * 8;
#pragma unroll
            for (int mi = 0; mi < 4; mi++)
                af[ch][mi] = *(const bf16x8*)(la + (wm * 64 + mi * 16 + lane16) * BK + pk);
#pragma unroll
            for (int ni = 0; ni < 2; ni++)
                bfr[ch][ni] = *(const bf16x8*)(lb + (wn * 32 + ni * 16 + lane16) * BK + pk);
        }
        // (2) async-stage NEXT tile into the other buffer (no alias with reads)
        if (it + 1 < nit) stage(cur ^ 1, (it + 1) * BK);
        // (3) MFMAs — vmcnt drain at the barrier lands after these
#pragma unroll
        for (int ch = 0; ch < 2; ch++)
#pragma unroll
            for (int mi = 0; mi < 4; mi++)
#pragma unroll
                for (int ni = 0; ni < 2; ni++)
                    acc[mi][ni] = __builtin_amdgcn_mfma_f32_16x16x32_bf16(
                        af[ch][mi], bfr[ch][ni], acc[mi][ni], 0, 0, 0);
        // (4) single barrier: next-staging drained AND current buffer released
        __syncthreads();
    };

    for (int it = 0; it < nit; it += 2) {
        body(0, it);
        body(1, it + 1);
    }

    // epilogue: C/D layout col=lane&15, row=quad*4+reg (m89-verified)
    float bv[2];
#pragma unroll
    for (int ni = 0; ni < 2; ni++)
        bv[ni] = bias[n0 + wn * 32 + ni * 16 + lane16];

#pragma unroll
    for (int mi = 0; mi < 4; mi++) {
        const int rbase = m0 + wm * 64 + mi * 16 + quad * 4;
#pragma unroll
        for (int ni = 0; ni < 2; ni++) {
            const int col = n0 + wn * 32 + ni * 16 + lane16;
#pragma unroll
            for (int r = 0; r < 4; r++)
                C[(size_t)(rbase + r) * N + col] = acc[mi][ni][r] + bv[ni];
        }
    }
}

extern "C" void kernel_launch(void* const* d_in, const int* in_sizes, int n_in,
                              void* d_out, int out_size, void* d_ws, size_t ws_size,
                              hipStream_t stream) {
    const float* input = (const float*)d_in[0];
    const float* mu    = (const float*)d_in[1];
    const float* rho   = (const float*)d_in[2];
    const float* eps   = (const float*)d_in[3];
    const float* bias  = (const float*)d_in[4];
    float* out = (float*)d_out;

    const int OUT = in_sizes[4];              // 2048
    const int IN  = in_sizes[1] / OUT;        // 2048
    const int M   = in_sizes[0] / IN;         // 4096

    unsigned short* in_bf = (unsigned short*)d_ws;                 // M*IN bf16
    unsigned short* w_bf  = in_bf + (size_t)M * IN;                // OUT*IN bf16

    const int nIn8 = (M * IN) / 8;
    const int nW8  = (OUT * IN) / 8;
    prep_kernel<<<dim3((nIn8 + nW8 + 255) / 256), 256, 0, stream>>>(
        input, mu, rho, eps, in_bf, w_bf, nIn8, nW8);

    gemm_bt_kernel<<<dim3(OUT / BN, M / BM), 512, 0, stream>>>(
        in_bf, w_bf, bias, out, M, OUT, IN);
}